// Round 6
// baseline (346.692 us; speedup 1.0000x reference)
//
#include <hip/hip_runtime.h>

// MultiHeadAttention3D: S=1024, B=8, E=1024, H=16, D=64.
// Pipeline: detect mask dtype -> cvt(f32->bf16) -> 3x proj GEMM (BK=64 dbuf,
//           in-block mask bitpack riding idle BW) -> V transpose ->
//           fused flash attention (swapped-QK, packed-bit mask) -> Wo GEMM (f32 out).

typedef __attribute__((ext_vector_type(8))) short bf16x8;       // MFMA A/B frag (8 bf16)
typedef __attribute__((ext_vector_type(8))) unsigned short u16x8;
typedef __attribute__((ext_vector_type(4))) float f32x4;

#define LOG2E 1.44269504088896340736f

__device__ __forceinline__ unsigned short bfbits(float f) {    // f32 -> bf16 (RTNE)
  unsigned u = __builtin_bit_cast(unsigned, f);
  u += 0x7fffu + ((u >> 16) & 1u);
  return (unsigned short)(u >> 16);
}
__device__ __forceinline__ unsigned pk2(float a, float b) {
  return (unsigned)bfbits(a) | ((unsigned)bfbits(b) << 16);
}
__device__ __forceinline__ void async16(const void* src, void* dst_lds) {
  __builtin_amdgcn_global_load_lds(
      (const __attribute__((address_space(1))) unsigned int*)src,
      (__attribute__((address_space(3))) unsigned int*)dst_lds, 16, 0, 0);
}
__device__ __forceinline__ unsigned nz4i(uint4 w) {            // 4 i32 words -> 4 bits
  return (w.x ? 1u : 0u) | (w.y ? 2u : 0u) | (w.z ? 4u : 0u) | (w.w ? 8u : 0u);
}
__device__ __forceinline__ unsigned nz4b(unsigned w) {         // 4 bytes -> 4 bits
  return ((w & 0xFFu) ? 1u : 0u) | ((w & 0xFF00u) ? 2u : 0u) |
         ((w & 0xFF0000u) ? 4u : 0u) | ((w & 0xFF000000u) ? 8u : 0u);
}

// ---------------- mask dtype detection ----------------
__global__ void detect_mask(const unsigned* __restrict__ m, int* __restrict__ flag)
{
  unsigned ok = 1u;
#pragma unroll 8
  for (int i = 0; i < 64; ++i) {
    unsigned w = m[(threadIdx.x << 6) + i];
    ok &= (w <= 1u) ? 1u : 0u;
  }
  unsigned long long vote = __ballot(ok != 0u);
  if (threadIdx.x == 0) *flag = (vote == ~0ull) ? 1 : 0;
}

// ---------------- convert q,k,v,W* to bf16 ----------------
__global__ __launch_bounds__(256) void cvt_kernel(
    const float* __restrict__ q, const float* __restrict__ k, const float* __restrict__ v,
    const float* __restrict__ wq, const float* __restrict__ wk,
    const float* __restrict__ wv, const float* __restrict__ wo,
    unsigned short* __restrict__ Xin, unsigned short* __restrict__ Wbf)
{
  const unsigned u = blockIdx.x * 256u + threadIdx.x;   // 3670016 units of 8 elems
  const float* src;
  unsigned short* dst;
  if (u < 3145728u) {                      // q,k,v
    const unsigned z = u >> 20, r = u & 1048575u;
    src = (z == 0 ? q : z == 1 ? k : v) + (size_t)r * 8;
    dst = Xin + (size_t)z * 8388608u + (size_t)r * 8;
  } else {                                 // Wq,Wk,Wv,Wo
    const unsigned u2 = u - 3145728u, wz = u2 >> 17, r = u2 & 131071u;
    src = (wz == 0 ? wq : wz == 1 ? wk : wz == 2 ? wv : wo) + (size_t)r * 8;
    dst = Wbf + (size_t)wz * 1048576u + (size_t)r * 8;
  }
  f32x4 a = *(const f32x4*)src;
  f32x4 b = *(const f32x4*)(src + 4);
  uint4 o;
  o.x = pk2(a[0], a[1]); o.y = pk2(a[2], a[3]);
  o.z = pk2(b[0], b[1]); o.w = pk2(b[2], b[3]);
  *(uint4*)dst = o;
}

// ---------------- GEMM (2-phase dbuf, BK=64) with in-block mask bitpack ----------------
// 256x128 tile, 8 waves (4Mx2N, 64x64 each), LDS 96 KiB, 256 blocks (1/CU).
// Each thread additionally packs up to 11 chunks of 32 mask words -> u32 bits,
// one chunk per K-iteration (kt<11): rides the idle HBM slots of the barrier drain.
template<int OUTF32>
__global__ __launch_bounds__(512) void gemm2ph(
    const unsigned short* __restrict__ A,  // [M][K] bf16
    const unsigned short* __restrict__ B,  // [N][K] bf16
    void* __restrict__ Cv, float scale, int M, int N, int K,
    const void* __restrict__ maskp, const int* __restrict__ mflag,
    unsigned* __restrict__ Mp32, unsigned packLo, unsigned packHi)
{
  const int tid = threadIdx.x;
  const int w = tid >> 6, lane = tid & 63, c = lane & 15, g = lane >> 4;
  const int wr = w >> 1, wc = w & 1;

  // XCD-chunked swizzle (256 blocks)
  const int bid = blockIdx.x;
  const int swz = (bid & 7) * 32 + (bid >> 3);
  const int ntx = N >> 7;
  const int bx = swz % ntx, by = swz / ntx;
  const int rowA = by * 256, rowB = bx * 128;

  __shared__ unsigned short As[2][256 * 64];   // 2 x 32 KiB
  __shared__ unsigned short Bs[2][128 * 64];   // 2 x 16 KiB

  const bool doPack = packHi > packLo;
  const unsigned slice0 = packLo + (unsigned)bid * 5462u;
  const unsigned slice1 = doPack ? (packHi < slice0 + 5462u ? packHi : slice0 + 5462u) : 0u;
  const bool mi32 = doPack && (*mflag != 0);

  f32x4 acc[4][4];
#pragma unroll
  for (int i = 0; i < 4; ++i)
#pragma unroll
    for (int j = 0; j < 4; ++j) acc[i][j] = (f32x4){0.f, 0.f, 0.f, 0.f};

  const int srow = tid >> 3, skc = tid & 7;
  const int wbase = (tid & ~63) * 16;          // wave-uniform LDS byte base

  // prologue: stage K-tile 0 into buf 0
#pragma unroll
  for (int i = 0; i < 4; ++i)
    async16(A + (size_t)(rowA + i * 64 + srow) * K + skc * 8,
            (char*)&As[0][0] + i * 8192 + wbase);
#pragma unroll
  for (int j = 0; j < 2; ++j)
    async16(B + (size_t)(rowB + j * 64 + srow) * K + skc * 8,
            (char*)&Bs[0][0] + j * 8192 + wbase);
  __syncthreads();

  int buf = 0;
  const int nk = K >> 6;
  for (int kt = 0; kt < nk; ++kt) {
    if (kt + 1 < nk) {                        // issue next-tile stage FIRST
      const int k1 = (kt + 1) << 6, bo = buf ^ 1;
#pragma unroll
      for (int i = 0; i < 4; ++i)
        async16(A + (size_t)(rowA + i * 64 + srow) * K + k1 + skc * 8,
                (char*)&As[bo][0] + i * 8192 + wbase);
#pragma unroll
      for (int j = 0; j < 2; ++j)
        async16(B + (size_t)(rowB + j * 64 + srow) * K + k1 + skc * 8,
                (char*)&Bs[bo][0] + j * 8192 + wbase);
    }
    // ---- mask bitpack slice (rides the barrier-drain BW) ----
    if (doPack && kt < 11) {
      const unsigned u = slice0 + (unsigned)kt * 512u + tid;
      if (u < slice1) {
        unsigned bits = 0u;
        if (mi32) {                            // 32 i32 words -> 32 bits
          const uint4* s = (const uint4*)((const int*)maskp + (size_t)u * 32);
#pragma unroll
          for (int hh = 0; hh < 2; ++hh) {
            const uint4 w0 = s[hh * 4 + 0], w1 = s[hh * 4 + 1];
            const uint4 w2 = s[hh * 4 + 2], w3 = s[hh * 4 + 3];
            const unsigned b16 = nz4i(w0) | (nz4i(w1) << 4) | (nz4i(w2) << 8) | (nz4i(w3) << 12);
            bits |= b16 << (hh * 16);
          }
        } else {                               // 32 u8 bytes -> 32 bits
          const uint4* s = (const uint4*)((const unsigned char*)maskp + (size_t)u * 32);
          const uint4 w0 = s[0], w1 = s[1];
          bits = nz4b(w0.x) | (nz4b(w0.y) << 4) | (nz4b(w0.z) << 8) | (nz4b(w0.w) << 12) |
                 (nz4b(w1.x) << 16) | (nz4b(w1.y) << 20) | (nz4b(w1.z) << 24) | (nz4b(w1.w) << 28);
        }
        Mp32[u] = bits;
      }
    }
    bf16x8 af[4][2], bfr[4][2];
#pragma unroll
    for (int x = 0; x < 4; ++x)
#pragma unroll
      for (int ks = 0; ks < 2; ++ks) {
        af[x][ks]  = *(const bf16x8*)&As[buf][(wr * 64 + x * 16 + c) * 64 + ks * 32 + (g << 3)];
        bfr[x][ks] = *(const bf16x8*)&Bs[buf][(wc * 64 + x * 16 + c) * 64 + ks * 32 + (g << 3)];
      }
#pragma unroll
    for (int ks = 0; ks < 2; ++ks)
#pragma unroll
      for (int mf = 0; mf < 4; ++mf)
#pragma unroll
        for (int nf = 0; nf < 4; ++nf)
          acc[mf][nf] = __builtin_amdgcn_mfma_f32_16x16x32_bf16(af[mf][ks], bfr[nf][ks], acc[mf][nf], 0, 0, 0);
    __syncthreads();                          // drains vmcnt(0): next tile + pack landed
    buf ^= 1;
  }

  const int r0 = rowA + wr * 64, c0 = rowB + wc * 64;
  if (OUTF32) {
    float* O = (float*)Cv;
#pragma unroll
    for (int mf = 0; mf < 4; ++mf)
#pragma unroll
      for (int nf = 0; nf < 4; ++nf)
#pragma unroll
        for (int j = 0; j < 4; ++j)
          O[(size_t)(r0 + mf * 16 + g * 4 + j) * N + c0 + nf * 16 + c] = acc[mf][nf][j] * scale;
  } else {
    unsigned short* O = (unsigned short*)Cv;
#pragma unroll
    for (int mf = 0; mf < 4; ++mf)
#pragma unroll
      for (int nf = 0; nf < 4; ++nf)
#pragma unroll
        for (int j = 0; j < 4; ++j)
          O[(size_t)(r0 + mf * 16 + g * 4 + j) * N + c0 + nf * 16 + c] = bfbits(acc[mf][nf][j] * scale);
  }
}

// ---------------- Vt[bh][d][s] = Vproj[(s*8+b)][h*64+d] ----------------
__global__ __launch_bounds__(256) void transpose_v(
    const unsigned short* __restrict__ Xp2, unsigned short* __restrict__ Vt)
{
  const int tid = threadIdx.x;
  const int bh = blockIdx.y, b = bh >> 4, h = bh & 15;
  const int s0 = blockIdx.x << 6;
  __shared__ unsigned short T[64 * 68];
#pragma unroll
  for (int p = 0; p < 2; ++p) {
    const int idx = (p << 8) + tid, sr = idx >> 3, ch2 = idx & 7;
    *(u16x8*)&T[sr * 68 + ch2 * 8] =
        *(const u16x8*)(Xp2 + ((size_t)((s0 + sr) * 8 + b) << 10) + (h << 6) + ch2 * 8);
  }
  __syncthreads();
#pragma unroll
  for (int p = 0; p < 2; ++p) {
    const int idx = (p << 8) + tid, dr = idx >> 3, ch2 = idx & 7;
    u16x8 o;
#pragma unroll
    for (int e = 0; e < 8; ++e) o[e] = T[(ch2 * 8 + e) * 68 + dr];
    *(u16x8*)(Vt + ((size_t)(bh * 64 + dr) << 10) + s0 + ch2 * 8) = o;
  }
}

// ---------------- fused flash attention (packed-bit mask) ----------------
__global__ __launch_bounds__(256) void attn_kernel(
    const unsigned short* __restrict__ Qp,   // [8192][1024] bf16, pre-scaled by 1/8
    const unsigned short* __restrict__ Kp,   // [8192][1024] bf16
    const unsigned short* __restrict__ Vt,   // [128][64][1024] bf16
    const unsigned long long* __restrict__ Mp, // [128*1024][16] packed mask bits
    unsigned short* __restrict__ AO)         // [8192][1024] bf16
{
  const int tid = threadIdx.x;
  const int w = tid >> 6, lane = tid & 63, c = lane & 15, g = lane >> 4;
  const int bh = blockIdx.y, b = bh >> 4, h = bh & 15;
  const int qb0 = blockIdx.x << 6;
  const int qrow = qb0 + (w << 4) + c;

  __shared__ unsigned short Ksm[64 * 72];       // [kk][d]
  __shared__ unsigned short Vsm[64 * 72];       // [d][kk]
  __shared__ unsigned short Psm[4][16 * 72];    // per-wave P[q][kk]

  bf16x8 qf[2];
  {
    const unsigned short* qp = Qp + ((size_t)(qrow * 8 + b) << 10) + (h << 6) + (g << 3);
    qf[0] = *(const bf16x8*)qp;
    qf[1] = *(const bf16x8*)(qp + 32);
  }

  const int row0 = tid >> 3, ch = tid & 7;
  const unsigned short* Vg = Vt + ((size_t)bh << 16);
  const unsigned long long* Mrow = Mp + (((size_t)bh << 10) + qrow) * 16;

  bf16x8 kr[2], vr[2];
#pragma unroll
  for (int p = 0; p < 2; ++p) {
    const int r = row0 + p * 32;
    kr[p] = *(const bf16x8*)(Kp + ((size_t)(r * 8 + b) << 10) + (h << 6) + (ch << 3));
    vr[p] = *(const bf16x8*)(Vg + ((size_t)r << 10) + (ch << 3));
  }
  unsigned long long mw = Mrow[0];

  f32x4 oacc[4];
#pragma unroll
  for (int i = 0; i < 4; ++i) oacc[i] = (f32x4){0.f, 0.f, 0.f, 0.f};
  float mrun = -1e30f, lrun = 0.f;

  for (int t = 0; t < 16; ++t) {
    const int kk0 = t << 6;
    __syncthreads();
#pragma unroll
    for (int p = 0; p < 2; ++p) {
      const int r = row0 + p * 32;
      *(bf16x8*)&Ksm[r * 72 + (ch << 3)] = kr[p];
      *(bf16x8*)&Vsm[r * 72 + (ch << 3)] = vr[p];
    }
    __syncthreads();
    unsigned long long mwN = 0ull;
    if (t < 15) {                                // prefetch next tile (K/V/mask)
      const int kk1 = kk0 + 64;
#pragma unroll
      for (int p = 0; p < 2; ++p) {
        const int r = row0 + p * 32;
        kr[p] = *(const bf16x8*)(Kp + ((size_t)((kk1 + r) * 8 + b) << 10) + (h << 6) + (ch << 3));
        vr[p] = *(const bf16x8*)(Vg + ((size_t)r << 10) + kk1 + (ch << 3));
      }
      mwN = Mrow[t + 1];
    }
    // S^T tile: rows kk = mf*16+g*4+j, col q = c
    f32x4 sacc[4];
#pragma unroll
    for (int i = 0; i < 4; ++i) sacc[i] = (f32x4){0.f, 0.f, 0.f, 0.f};
#pragma unroll
    for (int d2 = 0; d2 < 2; ++d2) {
#pragma unroll
      for (int mf = 0; mf < 4; ++mf) {
        bf16x8 kf = *(const bf16x8*)&Ksm[(mf * 16 + c) * 72 + d2 * 32 + (g << 3)];
        sacc[mf] = __builtin_amdgcn_mfma_f32_16x16x32_bf16(kf, qf[d2], sacc[mf], 0, 0, 0);
      }
    }
    // mask (bit-test) + online softmax
    float tmax = -1e30f;
#pragma unroll
    for (int mf = 0; mf < 4; ++mf) {
      const unsigned nib = ((unsigned)(mw >> (mf * 16 + (g << 2)))) & 0xFu;
#pragma unroll
      for (int j = 0; j < 4; ++j) {
        float s = sacc[mf][j];
        if ((nib >> j) & 1u) s = -1e30f;
        sacc[mf][j] = s;
        tmax = fmaxf(tmax, s);
      }
    }
    tmax = fmaxf(tmax, __shfl_xor(tmax, 16));
    tmax = fmaxf(tmax, __shfl_xor(tmax, 32));
    const float mnew = fmaxf(mrun, tmax);
    const float alpha = __builtin_amdgcn_exp2f((mrun - mnew) * LOG2E);
    float tsum = 0.f;
    float pv[4][4];
#pragma unroll
    for (int mf = 0; mf < 4; ++mf)
#pragma unroll
      for (int j = 0; j < 4; ++j) {
        const float p = __builtin_amdgcn_exp2f((sacc[mf][j] - mnew) * LOG2E);
        pv[mf][j] = p;
        tsum += p;
      }
    tsum += __shfl_xor(tsum, 16);
    tsum += __shfl_xor(tsum, 32);
    lrun = lrun * alpha + tsum;
    mrun = mnew;
#pragma unroll
    for (int i = 0; i < 4; ++i) {
      oacc[i][0] *= alpha; oacc[i][1] *= alpha; oacc[i][2] *= alpha; oacc[i][3] *= alpha;
    }
#pragma unroll
    for (int mf = 0; mf < 4; ++mf) {
      uint2 t2;
      t2.x = pk2(pv[mf][0], pv[mf][1]);
      t2.y = pk2(pv[mf][2], pv[mf][3]);
      *(uint2*)&Psm[w][c * 72 + mf * 16 + (g << 2)] = t2;
    }
#pragma unroll
    for (int ks = 0; ks < 2; ++ks) {
      bf16x8 pf = *(const bf16x8*)&Psm[w][c * 72 + ks * 32 + (g << 3)];
#pragma unroll
      for (int mf = 0; mf < 4; ++mf) {
        bf16x8 vf = *(const bf16x8*)&Vsm[(mf * 16 + c) * 72 + ks * 32 + (g << 3)];
        oacc[mf] = __builtin_amdgcn_mfma_f32_16x16x32_bf16(vf, pf, oacc[mf], 0, 0, 0);
      }
    }
    mw = mwN;
  }
  const float inv = 1.0f / lrun;
#pragma unroll
  for (int mf = 0; mf < 4; ++mf) {
    uint2 t2;
    t2.x = pk2(oacc[mf][0] * inv, oacc[mf][1] * inv);
    t2.y = pk2(oacc[mf][2] * inv, oacc[mf][3] * inv);
    *(uint2*)(AO + ((size_t)(qrow * 8 + b) << 10) + (h << 6) + mf * 16 + (g << 2)) = t2;
  }
}

// ---------------- host ----------------
extern "C" void kernel_launch(void* const* d_in, const int* in_sizes, int n_in,
                              void* d_out, int out_size, void* d_ws, size_t ws_size,
                              hipStream_t stream)
{
  const float* q  = (const float*)d_in[0];
  const float* k  = (const float*)d_in[1];
  const float* v  = (const float*)d_in[2];
  const void*  mask = (const void*)d_in[3];
  const float* wq = (const float*)d_in[4];
  const float* wk = (const float*)d_in[5];
  const float* wv = (const float*)d_in[6];
  const float* wo = (const float*)d_in[7];

  unsigned short* ws  = (unsigned short*)d_ws;   // ~126 MiB used
  unsigned short* Xin = ws;                      // 3 x 8388608 (bf16 q,k,v)
  unsigned short* Wbf = ws + 25165824u;          // 4 x 1048576
  unsigned short* Xp  = ws + 29360128u;          // 3 x 8388608 (projected)
  unsigned* Mp32      = (unsigned*)(ws + 54525952u);  // 4194304 u32 (16 MiB)
  int* mfl            = (int*)(ws + 62914560u);
  unsigned short* Vt  = ws + 8388608u;           // aliases Xin[1] (dead after K projection)
  unsigned short* AO  = ws;                      // aliases Xin[0] (dead after Q projection)

  const unsigned PT = 4194304u;                  // total pack units (u32, 32 mask words each)
  const unsigned p1 = 1398102u, p2 = 2796203u;   // thirds

  detect_mask<<<1, 64, 0, stream>>>((const unsigned*)mask, mfl);
  cvt_kernel<<<14336, 256, 0, stream>>>(q, k, v, wq, wk, wv, wo, Xin, Wbf);
  gemm2ph<0><<<256, 512, 0, stream>>>(Xin,             Wbf,            Xp,             0.125f, 8192, 1024, 1024,
                                      mask, mfl, Mp32, 0u, p1);
  gemm2ph<0><<<256, 512, 0, stream>>>(Xin + 8388608u,  Wbf + 1048576u, Xp + 8388608u,  1.0f,   8192, 1024, 1024,
                                      mask, mfl, Mp32, p1, p2);
  gemm2ph<0><<<256, 512, 0, stream>>>(Xin + 16777216u, Wbf + 2097152u, Xp + 16777216u, 1.0f,   8192, 1024, 1024,
                                      mask, mfl, Mp32, p2, PT);
  transpose_v<<<dim3(16, 128), 256, 0, stream>>>(Xp + 16777216u, Vt);
  attn_kernel<<<dim3(16, 128), 256, 0, stream>>>(Xp, Xp + 8388608u, Vt, (const unsigned long long*)Mp32, AO);
  gemm2ph<1><<<256, 512, 0, stream>>>(AO, Wbf + 3145728u, d_out, 1.0f, 8192, 1024, 1024,
                                      mask, mfl, Mp32, 0u, 0u);
}

// Round 7
// 309.382 us; speedup vs baseline: 1.1206x; 1.1206x over previous
//
#include <hip/hip_runtime.h>

// MultiHeadAttention3D: S=1024, B=8, E=1024, H=16, D=64.
// Pipeline: detect mask dtype -> cvt(f32->bf16) -> 3x proj GEMM (counted-vmcnt
//           dbuf 256x128, XOR-swizzled LDS) -> V transpose -> fused flash attention
//           (swapped-QK, direct i32 mask, setprio) -> Wo GEMM (f32 out).

typedef __attribute__((ext_vector_type(8))) short bf16x8;       // MFMA A/B frag (8 bf16)
typedef __attribute__((ext_vector_type(8))) unsigned short u16x8;
typedef __attribute__((ext_vector_type(4))) float f32x4;

#define LOG2E 1.44269504088896340736f

__device__ __forceinline__ unsigned short bfbits(float f) {    // f32 -> bf16 (RTNE)
  unsigned u = __builtin_bit_cast(unsigned, f);
  u += 0x7fffu + ((u >> 16) & 1u);
  return (unsigned short)(u >> 16);
}
__device__ __forceinline__ unsigned pk2(float a, float b) {
  return (unsigned)bfbits(a) | ((unsigned)bfbits(b) << 16);
}
__device__ __forceinline__ void async16(const void* src, void* dst_lds) {
  __builtin_amdgcn_global_load_lds(
      (const __attribute__((address_space(1))) unsigned int*)src,
      (__attribute__((address_space(3))) unsigned int*)dst_lds, 16, 0, 0);
}

// ---------------- mask dtype detection ----------------
__global__ void detect_mask(const unsigned* __restrict__ m, int* __restrict__ flag)
{
  unsigned ok = 1u;
#pragma unroll 8
  for (int i = 0; i < 64; ++i) {
    unsigned w = m[(threadIdx.x << 6) + i];
    ok &= (w <= 1u) ? 1u : 0u;
  }
  unsigned long long vote = __ballot(ok != 0u);
  if (threadIdx.x == 0) *flag = (vote == ~0ull) ? 1 : 0;
}

// ---------------- convert q,k,v,W* to bf16 ----------------
__global__ __launch_bounds__(256) void cvt_kernel(
    const float* __restrict__ q, const float* __restrict__ k, const float* __restrict__ v,
    const float* __restrict__ wq, const float* __restrict__ wk,
    const float* __restrict__ wv, const float* __restrict__ wo,
    unsigned short* __restrict__ Xin, unsigned short* __restrict__ Wbf)
{
  const unsigned u = blockIdx.x * 256u + threadIdx.x;   // 3670016 units of 8 elems
  const float* src;
  unsigned short* dst;
  if (u < 3145728u) {                      // q,k,v
    const unsigned z = u >> 20, r = u & 1048575u;
    src = (z == 0 ? q : z == 1 ? k : v) + (size_t)r * 8;
    dst = Xin + (size_t)z * 8388608u + (size_t)r * 8;
  } else {                                 // Wq,Wk,Wv,Wo
    const unsigned u2 = u - 3145728u, wz = u2 >> 17, r = u2 & 131071u;
    src = (wz == 0 ? wq : wz == 1 ? wk : wz == 2 ? wv : wo) + (size_t)r * 8;
    dst = Wbf + (size_t)wz * 1048576u + (size_t)r * 8;
  }
  f32x4 a = *(const f32x4*)src;
  f32x4 b = *(const f32x4*)(src + 4);
  uint4 o;
  o.x = pk2(a[0], a[1]); o.y = pk2(a[2], a[3]);
  o.z = pk2(b[0], b[1]); o.w = pk2(b[2], b[3]);
  *(uint4*)dst = o;
}

// ---------------- GEMM: counted-vmcnt double-buffer, 256x128, BK=64 ----------------
// 8 waves (4Mx2N, 64x64 each), LDS 96 KiB, 256 blocks (1/CU).
// Schedule per iter: vmcnt(6) [tile t landed, t+1 in flight] -> barrier ->
// ds_read+MFMA(buf t) -> barrier -> stage(t+2 -> buf t). Raw s_barrier keeps
// prefetch loads in flight across barriers (T4). LDS XOR chunk swizzle via
// pre-swizzled global source (rule #21): 16-way ds_read bank conflict -> 2-way.
template<int OUTF32>
__global__ __launch_bounds__(512) void gemm2ph(
    const unsigned short* __restrict__ A,  // [M][K] bf16
    const unsigned short* __restrict__ B,  // [N][K] bf16
    void* __restrict__ Cv, float scale, int M, int N, int K)
{
  const int tid = threadIdx.x;
  const int w = tid >> 6, lane = tid & 63, c = lane & 15, g = lane >> 4;
  const int wr = w >> 1, wc = w & 1;

  // XCD-chunked swizzle (256 blocks)
  const int bid = blockIdx.x;
  const int swz = (bid & 7) * 32 + (bid >> 3);
  const int ntx = N >> 7;
  const int bx = swz % ntx, by = swz / ntx;
  const int rowA = by * 256, rowB = bx * 128;

  __shared__ unsigned short As[2][256 * 64];   // 2 x 32 KiB
  __shared__ unsigned short Bs[2][128 * 64];   // 2 x 16 KiB

  f32x4 acc[4][4];
#pragma unroll
  for (int i = 0; i < 4; ++i)
#pragma unroll
    for (int j = 0; j < 4; ++j) acc[i][j] = (f32x4){0.f, 0.f, 0.f, 0.f};

  const int srow = tid >> 3;
  const int skc = (tid & 7) ^ (srow & 7);      // pre-swizzled global 16B-chunk
  const int wbase = (tid & ~63) * 16;          // wave-uniform LDS byte base (linear dest)

#define STAGE(kt_, bb_) do { const int k0_ = (kt_) << 6;                          \
    _Pragma("unroll") for (int i_ = 0; i_ < 4; ++i_)                              \
      async16(A + (size_t)(rowA + i_ * 64 + srow) * K + k0_ + skc * 8,            \
              (char*)&As[bb_][0] + i_ * 8192 + wbase);                            \
    _Pragma("unroll") for (int j_ = 0; j_ < 2; ++j_)                              \
      async16(B + (size_t)(rowB + j_ * 64 + srow) * K + k0_ + skc * 8,            \
              (char*)&Bs[bb_][0] + j_ * 8192 + wbase); } while (0)

  // swizzled read offset (elements): row*64 + ((ks*4+g)^(row&7))*8; row&7 == c&7
#define RD(arr_, bb_, row_, ks_) \
    (*(const bf16x8*)&arr_[bb_][(row_) * 64 + ((((ks_) * 4 + g) ^ (c & 7)) << 3)])

#define COMPUTE(bb_) do {                                                         \
    bf16x8 af_[4][2], bf_[4][2];                                                  \
    _Pragma("unroll") for (int x_ = 0; x_ < 4; ++x_)                              \
      _Pragma("unroll") for (int ks_ = 0; ks_ < 2; ++ks_) {                       \
        af_[x_][ks_] = RD(As, bb_, wr * 64 + x_ * 16 + c, ks_);                   \
        bf_[x_][ks_] = RD(Bs, bb_, wc * 64 + x_ * 16 + c, ks_);                   \
      }                                                                           \
    _Pragma("unroll") for (int ks_ = 0; ks_ < 2; ++ks_)                           \
      _Pragma("unroll") for (int mf_ = 0; mf_ < 4; ++mf_)                         \
        _Pragma("unroll") for (int nf_ = 0; nf_ < 4; ++nf_)                       \
          acc[mf_][nf_] = __builtin_amdgcn_mfma_f32_16x16x32_bf16(                \
              af_[mf_][ks_], bf_[nf_][ks_], acc[mf_][nf_], 0, 0, 0); } while (0)

  STAGE(0, 0);
  STAGE(1, 1);

  for (int kt = 0; kt < 15; ++kt) {
    asm volatile("s_waitcnt vmcnt(6)" ::: "memory");   // tile kt landed; kt+1 in flight
    __builtin_amdgcn_sched_barrier(0);
    __builtin_amdgcn_s_barrier();
    __builtin_amdgcn_sched_barrier(0);
    const int buf = kt & 1;
    COMPUTE(buf);
    __builtin_amdgcn_sched_barrier(0);
    __builtin_amdgcn_s_barrier();                      // all waves done reading buf
    __builtin_amdgcn_sched_barrier(0);
    if (kt < 14) STAGE(kt + 2, buf);                   // overwrite just-computed buf
  }
  asm volatile("s_waitcnt vmcnt(0)" ::: "memory");     // tile 15 landed
  __builtin_amdgcn_sched_barrier(0);
  __builtin_amdgcn_s_barrier();
  __builtin_amdgcn_sched_barrier(0);
  COMPUTE(1);

#undef STAGE
#undef RD
#undef COMPUTE

  const int r0 = rowA + wr * 64, c0 = rowB + wc * 64;
  if (OUTF32) {
    float* O = (float*)Cv;
#pragma unroll
    for (int mf = 0; mf < 4; ++mf)
#pragma unroll
      for (int nf = 0; nf < 4; ++nf)
#pragma unroll
        for (int j = 0; j < 4; ++j)
          O[(size_t)(r0 + mf * 16 + g * 4 + j) * N + c0 + nf * 16 + c] = acc[mf][nf][j] * scale;
  } else {
    unsigned short* O = (unsigned short*)Cv;
#pragma unroll
    for (int mf = 0; mf < 4; ++mf)
#pragma unroll
      for (int nf = 0; nf < 4; ++nf)
#pragma unroll
        for (int j = 0; j < 4; ++j)
          O[(size_t)(r0 + mf * 16 + g * 4 + j) * N + c0 + nf * 16 + c] = bfbits(acc[mf][nf][j] * scale);
  }
}

// ---------------- Vt[bh][d][s] = Vproj[(s*8+b)][h*64+d] ----------------
__global__ __launch_bounds__(256) void transpose_v(
    const unsigned short* __restrict__ Xp2, unsigned short* __restrict__ Vt)
{
  const int tid = threadIdx.x;
  const int bh = blockIdx.y, b = bh >> 4, h = bh & 15;
  const int s0 = blockIdx.x << 6;
  __shared__ unsigned short T[64 * 68];
#pragma unroll
  for (int p = 0; p < 2; ++p) {
    const int idx = (p << 8) + tid, sr = idx >> 3, ch2 = idx & 7;
    *(u16x8*)&T[sr * 68 + ch2 * 8] =
        *(const u16x8*)(Xp2 + ((size_t)((s0 + sr) * 8 + b) << 10) + (h << 6) + ch2 * 8);
  }
  __syncthreads();
#pragma unroll
  for (int p = 0; p < 2; ++p) {
    const int idx = (p << 8) + tid, dr = idx >> 3, ch2 = idx & 7;
    u16x8 o;
#pragma unroll
    for (int e = 0; e < 8; ++e) o[e] = T[(ch2 * 8 + e) * 68 + dr];
    *(u16x8*)(Vt + ((size_t)(bh * 64 + dr) << 10) + s0 + ch2 * 8) = o;
  }
}

// ---------------- mask fragment load (u8 or i32) ----------------
__device__ __forceinline__ void load_mask4(unsigned mv[4], const void* maskp, bool mi32,
                                           size_t base, int g) {
  if (mi32) {
    const int* mrow = (const int*)maskp + base + (g << 2);
#pragma unroll
    for (int mf = 0; mf < 4; ++mf) {
      const int4 w4 = *(const int4*)(mrow + mf * 16);
      mv[mf] = (w4.x ? 1u : 0u) | (w4.y ? 0x100u : 0u) | (w4.z ? 0x10000u : 0u) | (w4.w ? 0x1000000u : 0u);
    }
  } else {
    const unsigned char* mrow = (const unsigned char*)maskp + base + (g << 2);
#pragma unroll
    for (int mf = 0; mf < 4; ++mf) mv[mf] = *(const unsigned*)(mrow + mf * 16);
  }
}

// ---------------- fused flash attention ----------------
// grid (16 qblocks, 128 bh), 256 thr. Wave w owns q-rows [qb0+16w, +16).
// S^T = K*Q^T (softmax rows lane-local, q = lane&15); O^T = V^T * P^T.
__global__ __launch_bounds__(256) void attn_kernel(
    const unsigned short* __restrict__ Qp,   // [8192][1024] bf16, pre-scaled by 1/8
    const unsigned short* __restrict__ Kp,   // [8192][1024] bf16
    const unsigned short* __restrict__ Vt,   // [128][64][1024] bf16
    const void*           __restrict__ maskp,// [128][1024][1024] u8 or i32
    const int*            __restrict__ mflag,
    unsigned short* __restrict__ AO)         // [8192][1024] bf16
{
  const int tid = threadIdx.x;
  const int w = tid >> 6, lane = tid & 63, c = lane & 15, g = lane >> 4;
  const int bh = blockIdx.y, b = bh >> 4, h = bh & 15;
  const int qb0 = blockIdx.x << 6;
  const int qrow = qb0 + (w << 4) + c;
  const bool mi32 = (*mflag != 0);

  __shared__ unsigned short Ksm[64 * 72];       // [kk][d]
  __shared__ unsigned short Vsm[64 * 72];       // [d][kk]
  __shared__ unsigned short Psm[4][16 * 72];    // per-wave P[q][kk]

  bf16x8 qf[2];
  {
    const unsigned short* qp = Qp + ((size_t)(qrow * 8 + b) << 10) + (h << 6) + (g << 3);
    qf[0] = *(const bf16x8*)qp;
    qf[1] = *(const bf16x8*)(qp + 32);
  }

  const int row0 = tid >> 3, ch = tid & 7;
  const unsigned short* Vg = Vt + ((size_t)bh << 16);
  const size_t mbase0 = ((size_t)bh << 20) + ((size_t)qrow << 10);

  bf16x8 kr[2], vr[2];
#pragma unroll
  for (int p = 0; p < 2; ++p) {
    const int r = row0 + p * 32;
    kr[p] = *(const bf16x8*)(Kp + ((size_t)(r * 8 + b) << 10) + (h << 6) + (ch << 3));
    vr[p] = *(const bf16x8*)(Vg + ((size_t)r << 10) + (ch << 3));
  }
  unsigned mv[4];
  load_mask4(mv, maskp, mi32, mbase0, g);       // tile 0 mask prefetch

  f32x4 oacc[4];
#pragma unroll
  for (int i = 0; i < 4; ++i) oacc[i] = (f32x4){0.f, 0.f, 0.f, 0.f};
  float mrun = -1e30f, lrun = 0.f;

  for (int t = 0; t < 16; ++t) {
    const int kk0 = t << 6;
    __syncthreads();
#pragma unroll
    for (int p = 0; p < 2; ++p) {
      const int r = row0 + p * 32;
      *(bf16x8*)&Ksm[r * 72 + (ch << 3)] = kr[p];
      *(bf16x8*)&Vsm[r * 72 + (ch << 3)] = vr[p];
    }
    __syncthreads();
    unsigned mvN[4];
    if (t < 15) {                                // prefetch next tile (K/V/mask)
      const int kk1 = kk0 + 64;
#pragma unroll
      for (int p = 0; p < 2; ++p) {
        const int r = row0 + p * 32;
        kr[p] = *(const bf16x8*)(Kp + ((size_t)((kk1 + r) * 8 + b) << 10) + (h << 6) + (ch << 3));
        vr[p] = *(const bf16x8*)(Vg + ((size_t)r << 10) + kk1 + (ch << 3));
      }
      load_mask4(mvN, maskp, mi32, mbase0 + kk1, g);
    }
    // S^T tile: rows kk = mf*16+g*4+j, col q = c
    f32x4 sacc[4];
#pragma unroll
    for (int i = 0; i < 4; ++i) sacc[i] = (f32x4){0.f, 0.f, 0.f, 0.f};
    __builtin_amdgcn_s_setprio(1);
#pragma unroll
    for (int d2 = 0; d2 < 2; ++d2) {
#pragma unroll
      for (int mf = 0; mf < 4; ++mf) {
        bf16x8 kf = *(const bf16x8*)&Ksm[(mf * 16 + c) * 72 + d2 * 32 + (g << 3)];
        sacc[mf] = __builtin_amdgcn_mfma_f32_16x16x32_bf16(kf, qf[d2], sacc[mf], 0, 0, 0);
      }
    }
    __builtin_amdgcn_s_setprio(0);
    // mask + online softmax
    float tmax = -1e30f;
#pragma unroll
    for (int mf = 0; mf < 4; ++mf)
#pragma unroll
      for (int j = 0; j < 4; ++j) {
        float s = sacc[mf][j];
        if ((mv[mf] >> (8 * j)) & 0xffu) s = -1e30f;
        sacc[mf][j] = s;
        tmax = fmaxf(tmax, s);
      }
    tmax = fmaxf(tmax, __shfl_xor(tmax, 16));
    tmax = fmaxf(tmax, __shfl_xor(tmax, 32));
    const float mnew = fmaxf(mrun, tmax);
    const float alpha = __builtin_amdgcn_exp2f((mrun - mnew) * LOG2E);
    float tsum = 0.f;
    float pv[4][4];
#pragma unroll
    for (int mf = 0; mf < 4; ++mf)
#pragma unroll
      for (int j = 0; j < 4; ++j) {
        const float p = __builtin_amdgcn_exp2f((sacc[mf][j] - mnew) * LOG2E);
        pv[mf][j] = p;
        tsum += p;
      }
    tsum += __shfl_xor(tsum, 16);
    tsum += __shfl_xor(tsum, 32);
    lrun = lrun * alpha + tsum;
    mrun = mnew;
#pragma unroll
    for (int i = 0; i < 4; ++i) {
      oacc[i][0] *= alpha; oacc[i][1] *= alpha; oacc[i][2] *= alpha; oacc[i][3] *= alpha;
    }
#pragma unroll
    for (int mf = 0; mf < 4; ++mf) {
      uint2 t2;
      t2.x = pk2(pv[mf][0], pv[mf][1]);
      t2.y = pk2(pv[mf][2], pv[mf][3]);
      *(uint2*)&Psm[w][c * 72 + mf * 16 + (g << 2)] = t2;
    }
    __builtin_amdgcn_s_setprio(1);
#pragma unroll
    for (int ks = 0; ks < 2; ++ks) {
      bf16x8 pf = *(const bf16x8*)&Psm[w][c * 72 + ks * 32 + (g << 3)];
#pragma unroll
      for (int mf = 0; mf < 4; ++mf) {
        bf16x8 vf = *(const bf16x8*)&Vsm[(mf * 16 + c) * 72 + ks * 32 + (g << 3)];
        oacc[mf] = __builtin_amdgcn_mfma_f32_16x16x32_bf16(vf, pf, oacc[mf], 0, 0, 0);
      }
    }
    __builtin_amdgcn_s_setprio(0);
#pragma unroll
    for (int i = 0; i < 4; ++i) mv[i] = mvN[i];
  }
  const float inv = 1.0f / lrun;
#pragma unroll
  for (int mf = 0; mf < 4; ++mf) {
    uint2 t2;
    t2.x = pk2(oacc[mf][0] * inv, oacc[mf][1] * inv);
    t2.y = pk2(oacc[mf][2] * inv, oacc[mf][3] * inv);
    *(uint2*)(AO + ((size_t)(qrow * 8 + b) << 10) + (h << 6) + mf * 16 + (g << 2)) = t2;
  }
}

// ---------------- host ----------------
extern "C" void kernel_launch(void* const* d_in, const int* in_sizes, int n_in,
                              void* d_out, int out_size, void* d_ws, size_t ws_size,
                              hipStream_t stream)
{
  const float* q  = (const float*)d_in[0];
  const float* k  = (const float*)d_in[1];
  const float* v  = (const float*)d_in[2];
  const void*  mask = (const void*)d_in[3];
  const float* wq = (const float*)d_in[4];
  const float* wk = (const float*)d_in[5];
  const float* wv = (const float*)d_in[6];
  const float* wo = (const float*)d_in[7];

  unsigned short* ws  = (unsigned short*)d_ws;   // ~104 MiB used
  unsigned short* Xin = ws;                      // 3 x 8388608 (bf16 q,k,v)
  unsigned short* Wbf = ws + 25165824u;          // 4 x 1048576
  unsigned short* Xp  = ws + 29360128u;          // 3 x 8388608 (projected)
  int* mfl            = (int*)(ws + 54525952u);
  unsigned short* Vt  = ws + 8388608u;           // aliases Xin[1] (dead after K projection)
  unsigned short* AO  = ws;                      // aliases Xin[0] (dead after Q projection)

  detect_mask<<<1, 64, 0, stream>>>((const unsigned*)mask, mfl);
  cvt_kernel<<<14336, 256, 0, stream>>>(q, k, v, wq, wk, wv, wo, Xin, Wbf);
  gemm2ph<0><<<256, 512, 0, stream>>>(Xin,             Wbf,            Xp,             0.125f, 8192, 1024, 1024);
  gemm2ph<0><<<256, 512, 0, stream>>>(Xin + 8388608u,  Wbf + 1048576u, Xp + 8388608u,  1.0f,   8192, 1024, 1024);
  gemm2ph<0><<<256, 512, 0, stream>>>(Xin + 16777216u, Wbf + 2097152u, Xp + 16777216u, 1.0f,   8192, 1024, 1024);
  transpose_v<<<dim3(16, 128), 256, 0, stream>>>(Xp + 16777216u, Vt);
  attn_kernel<<<dim3(16, 128), 256, 0, stream>>>(Xp, Xp + 8388608u, Vt, mask, mfl, AO);
  gemm2ph<1><<<256, 512, 0, stream>>>(AO, Wbf + 3145728u, d_out, 1.0f, 8192, 1024, 1024);
}

// Round 8
// 292.327 us; speedup vs baseline: 1.1860x; 1.0583x over previous
//
#include <hip/hip_runtime.h>

// MultiHeadAttention3D: S=1024, B=8, E=1024, H=16, D=64.
// Pipeline: detect mask dtype -> cvt(f32->bf16) -> merged QKV proj GEMM (128x128,
//           counted-vmcnt dbuf, 2 blocks/CU) -> V transpose -> fused flash attention
//           (swapped-QK, direct i32 mask) -> Wo GEMM (f32 out).

typedef __attribute__((ext_vector_type(8))) short bf16x8;       // MFMA A/B frag (8 bf16)
typedef __attribute__((ext_vector_type(8))) unsigned short u16x8;
typedef __attribute__((ext_vector_type(4))) float f32x4;

#define LOG2E 1.44269504088896340736f

__device__ __forceinline__ unsigned short bfbits(float f) {    // f32 -> bf16 (RTNE)
  unsigned u = __builtin_bit_cast(unsigned, f);
  u += 0x7fffu + ((u >> 16) & 1u);
  return (unsigned short)(u >> 16);
}
__device__ __forceinline__ unsigned pk2(float a, float b) {
  return (unsigned)bfbits(a) | ((unsigned)bfbits(b) << 16);
}
__device__ __forceinline__ void async16(const void* src, void* dst_lds) {
  __builtin_amdgcn_global_load_lds(
      (const __attribute__((address_space(1))) unsigned int*)src,
      (__attribute__((address_space(3))) unsigned int*)dst_lds, 16, 0, 0);
}

// ---------------- mask dtype detection ----------------
__global__ void detect_mask(const unsigned* __restrict__ m, int* __restrict__ flag)
{
  unsigned ok = 1u;
#pragma unroll 8
  for (int i = 0; i < 64; ++i) {
    unsigned w = m[(threadIdx.x << 6) + i];
    ok &= (w <= 1u) ? 1u : 0u;
  }
  unsigned long long vote = __ballot(ok != 0u);
  if (threadIdx.x == 0) *flag = (vote == ~0ull) ? 1 : 0;
}

// ---------------- convert q,k,v,W* to bf16 ----------------
__global__ __launch_bounds__(256) void cvt_kernel(
    const float* __restrict__ q, const float* __restrict__ k, const float* __restrict__ v,
    const float* __restrict__ wq, const float* __restrict__ wk,
    const float* __restrict__ wv, const float* __restrict__ wo,
    unsigned short* __restrict__ Xin, unsigned short* __restrict__ Wbf)
{
  const unsigned u = blockIdx.x * 256u + threadIdx.x;   // 3670016 units of 8 elems
  const float* src;
  unsigned short* dst;
  if (u < 3145728u) {                      // q,k,v
    const unsigned z = u >> 20, r = u & 1048575u;
    src = (z == 0 ? q : z == 1 ? k : v) + (size_t)r * 8;
    dst = Xin + (size_t)z * 8388608u + (size_t)r * 8;
  } else {                                 // Wq,Wk,Wv,Wo
    const unsigned u2 = u - 3145728u, wz = u2 >> 17, r = u2 & 131071u;
    src = (wz == 0 ? wq : wz == 1 ? wk : wz == 2 ? wv : wo) + (size_t)r * 8;
    dst = Wbf + (size_t)wz * 1048576u + (size_t)r * 8;
  }
  f32x4 a = *(const f32x4*)src;
  f32x4 b = *(const f32x4*)(src + 4);
  uint4 o;
  o.x = pk2(a[0], a[1]); o.y = pk2(a[2], a[3]);
  o.z = pk2(b[0], b[1]); o.w = pk2(b[2], b[3]);
  *(uint4*)dst = o;
}

// ---------------- GEMM: 128x128 tile, BK=64, counted-vmcnt dbuf, 2 blocks/CU ----------------
// 4 waves (2x2, 64x64 each), LDS 64 KiB. nproj sub-GEMMs of 512 blocks each
// (p = bid>>9). Schedule: vmcnt(8) [tile t landed, t+1 in flight] -> barrier ->
// ds_read+MFMA -> barrier -> stage(t+2). XOR chunk swizzle (rule #21).
template<int OUTF32>
__global__ __launch_bounds__(256) void gemm128(
    const unsigned short* __restrict__ A0,  // [M][K] bf16 (+ p*Asd)
    const unsigned short* __restrict__ B0,  // [N][K] bf16 (+ p*Bsd)
    void* __restrict__ C0, float scale0, int M, int N, int K)
{
  const int tid = threadIdx.x;
  const int w = tid >> 6, lane = tid & 63, c = lane & 15, g = lane >> 4;
  const int wr = w >> 1, wc = w & 1;

  const int bid = blockIdx.x;
  const int p = bid >> 9, local = bid & 511;
  const unsigned short* A = A0 + (size_t)p * 8388608u;
  const unsigned short* B = B0 + (size_t)p * 1048576u;
  const float scale = (p == 0) ? scale0 : 1.0f;

  // XCD-chunked swizzle within the 512-block sub-grid
  const int swz = (local & 7) * 64 + (local >> 3);
  const int ntx = N >> 7;
  const int bx = swz % ntx, by = swz / ntx;
  const int rowA = by * 128, rowB = bx * 128;

  __shared__ unsigned short As[2][128 * 64];   // 2 x 16 KiB
  __shared__ unsigned short Bs[2][128 * 64];   // 2 x 16 KiB

  f32x4 acc[4][4];
#pragma unroll
  for (int i = 0; i < 4; ++i)
#pragma unroll
    for (int j = 0; j < 4; ++j) acc[i][j] = (f32x4){0.f, 0.f, 0.f, 0.f};

  const int wbase = (tid & ~63) * 16;          // wave-uniform LDS byte base (linear dest)

#define STAGE(kt_, bb_) do { const int k0_ = (kt_) << 6;                          \
    _Pragma("unroll") for (int i_ = 0; i_ < 4; ++i_) {                            \
      const int slot_ = i_ * 256 + tid;                                           \
      const int row_ = slot_ >> 3;                                                \
      const int kc_ = (slot_ & 7) ^ (row_ & 7);                                   \
      async16(A + (size_t)(rowA + row_) * K + k0_ + kc_ * 8,                      \
              (char*)&As[bb_][0] + (i_ << 12) + wbase);                           \
      async16(B + (size_t)(rowB + row_) * K + k0_ + kc_ * 8,                      \
              (char*)&Bs[bb_][0] + (i_ << 12) + wbase);                           \
    } } while (0)

  // LDS[row][j] holds global chunk j^(row&7); to read chunk (ks*4+g): j = (ks*4+g)^(row&7)
#define RD(arr_, bb_, row_, ks_) \
    (*(const bf16x8*)&arr_[bb_][(row_) * 64 + ((((ks_) * 4 + g) ^ ((row_) & 7)) << 3)])

#define COMPUTE(bb_) do {                                                         \
    bf16x8 af_[4][2], bf_[4][2];                                                  \
    _Pragma("unroll") for (int x_ = 0; x_ < 4; ++x_)                              \
      _Pragma("unroll") for (int ks_ = 0; ks_ < 2; ++ks_) {                       \
        af_[x_][ks_] = RD(As, bb_, wr * 64 + x_ * 16 + c, ks_);                   \
        bf_[x_][ks_] = RD(Bs, bb_, wc * 64 + x_ * 16 + c, ks_);                   \
      }                                                                           \
    _Pragma("unroll") for (int ks_ = 0; ks_ < 2; ++ks_)                           \
      _Pragma("unroll") for (int mf_ = 0; mf_ < 4; ++mf_)                         \
        _Pragma("unroll") for (int nf_ = 0; nf_ < 4; ++nf_)                       \
          acc[mf_][nf_] = __builtin_amdgcn_mfma_f32_16x16x32_bf16(                \
              af_[mf_][ks_], bf_[nf_][ks_], acc[mf_][nf_], 0, 0, 0); } while (0)

  STAGE(0, 0);
  STAGE(1, 1);

  for (int kt = 0; kt < 15; ++kt) {
    asm volatile("s_waitcnt vmcnt(8)" ::: "memory");   // tile kt landed; kt+1 in flight
    __builtin_amdgcn_sched_barrier(0);
    __builtin_amdgcn_s_barrier();
    __builtin_amdgcn_sched_barrier(0);
    const int buf = kt & 1;
    COMPUTE(buf);
    __builtin_amdgcn_sched_barrier(0);
    __builtin_amdgcn_s_barrier();                      // all waves done reading buf
    __builtin_amdgcn_sched_barrier(0);
    if (kt < 14) STAGE(kt + 2, buf);                   // overwrite just-computed buf
  }
  asm volatile("s_waitcnt vmcnt(0)" ::: "memory");     // tile 15 landed
  __builtin_amdgcn_sched_barrier(0);
  __builtin_amdgcn_s_barrier();
  __builtin_amdgcn_sched_barrier(0);
  COMPUTE(1);

#undef STAGE
#undef RD
#undef COMPUTE

  const int r0 = rowA + wr * 64, c0 = rowB + wc * 64;
  if (OUTF32) {
    float* O = (float*)C0;
#pragma unroll
    for (int mf = 0; mf < 4; ++mf)
#pragma unroll
      for (int nf = 0; nf < 4; ++nf)
#pragma unroll
        for (int j = 0; j < 4; ++j)
          O[(size_t)(r0 + mf * 16 + g * 4 + j) * N + c0 + nf * 16 + c] = acc[mf][nf][j] * scale;
  } else {
    unsigned short* O = (unsigned short*)C0 + (size_t)p * 8388608u;
#pragma unroll
    for (int mf = 0; mf < 4; ++mf)
#pragma unroll
      for (int nf = 0; nf < 4; ++nf)
#pragma unroll
        for (int j = 0; j < 4; ++j)
          O[(size_t)(r0 + mf * 16 + g * 4 + j) * N + c0 + nf * 16 + c] = bfbits(acc[mf][nf][j] * scale);
  }
}

// ---------------- Vt[bh][d][s] = Vproj[(s*8+b)][h*64+d] ----------------
__global__ __launch_bounds__(256) void transpose_v(
    const unsigned short* __restrict__ Xp2, unsigned short* __restrict__ Vt)
{
  const int tid = threadIdx.x;
  const int bh = blockIdx.y, b = bh >> 4, h = bh & 15;
  const int s0 = blockIdx.x << 6;
  __shared__ unsigned short T[64 * 68];
#pragma unroll
  for (int p = 0; p < 2; ++p) {
    const int idx = (p << 8) + tid, sr = idx >> 3, ch2 = idx & 7;
    *(u16x8*)&T[sr * 68 + ch2 * 8] =
        *(const u16x8*)(Xp2 + ((size_t)((s0 + sr) * 8 + b) << 10) + (h << 6) + ch2 * 8);
  }
  __syncthreads();
#pragma unroll
  for (int p = 0; p < 2; ++p) {
    const int idx = (p << 8) + tid, dr = idx >> 3, ch2 = idx & 7;
    u16x8 o;
#pragma unroll
    for (int e = 0; e < 8; ++e) o[e] = T[(ch2 * 8 + e) * 68 + dr];
    *(u16x8*)(Vt + ((size_t)(bh * 64 + dr) << 10) + s0 + ch2 * 8) = o;
  }
}

// ---------------- mask fragment load (u8 or i32) ----------------
__device__ __forceinline__ void load_mask4(unsigned mv[4], const void* maskp, bool mi32,
                                           size_t base, int g) {
  if (mi32) {
    const int* mrow = (const int*)maskp + base + (g << 2);
#pragma unroll
    for (int mf = 0; mf < 4; ++mf) {
      const int4 w4 = *(const int4*)(mrow + mf * 16);
      mv[mf] = (w4.x ? 1u : 0u) | (w4.y ? 0x100u : 0u) | (w4.z ? 0x10000u : 0u) | (w4.w ? 0x1000000u : 0u);
    }
  } else {
    const unsigned char* mrow = (const unsigned char*)maskp + base + (g << 2);
#pragma unroll
    for (int mf = 0; mf < 4; ++mf) mv[mf] = *(const unsigned*)(mrow + mf * 16);
  }
}

// ---------------- fused flash attention ----------------
// grid (16 qblocks, 128 bh), 256 thr. Wave w owns q-rows [qb0+16w, +16).
// S^T = K*Q^T (softmax rows lane-local, q = lane&15); O^T = V^T * P^T.
__global__ __launch_bounds__(256) void attn_kernel(
    const unsigned short* __restrict__ Qp,   // [8192][1024] bf16, pre-scaled by 1/8
    const unsigned short* __restrict__ Kp,   // [8192][1024] bf16
    const unsigned short* __restrict__ Vt,   // [128][64][1024] bf16
    const void*           __restrict__ maskp,// [128][1024][1024] u8 or i32
    const int*            __restrict__ mflag,
    unsigned short* __restrict__ AO)         // [8192][1024] bf16
{
  const int tid = threadIdx.x;
  const int w = tid >> 6, lane = tid & 63, c = lane & 15, g = lane >> 4;
  const int bh = blockIdx.y, b = bh >> 4, h = bh & 15;
  const int qb0 = blockIdx.x << 6;
  const int qrow = qb0 + (w << 4) + c;
  const bool mi32 = (*mflag != 0);

  __shared__ unsigned short Ksm[64 * 72];       // [kk][d]
  __shared__ unsigned short Vsm[64 * 72];       // [d][kk]
  __shared__ unsigned short Psm[4][16 * 72];    // per-wave P[q][kk]

  bf16x8 qf[2];
  {
    const unsigned short* qp = Qp + ((size_t)(qrow * 8 + b) << 10) + (h << 6) + (g << 3);
    qf[0] = *(const bf16x8*)qp;
    qf[1] = *(const bf16x8*)(qp + 32);
  }

  const int row0 = tid >> 3, ch = tid & 7;
  const unsigned short* Vg = Vt + ((size_t)bh << 16);
  const size_t mbase0 = ((size_t)bh << 20) + ((size_t)qrow << 10);

  bf16x8 kr[2], vr[2];
#pragma unroll
  for (int p = 0; p < 2; ++p) {
    const int r = row0 + p * 32;
    kr[p] = *(const bf16x8*)(Kp + ((size_t)(r * 8 + b) << 10) + (h << 6) + (ch << 3));
    vr[p] = *(const bf16x8*)(Vg + ((size_t)r << 10) + (ch << 3));
  }
  unsigned mv[4];
  load_mask4(mv, maskp, mi32, mbase0, g);       // tile 0 mask prefetch

  f32x4 oacc[4];
#pragma unroll
  for (int i = 0; i < 4; ++i) oacc[i] = (f32x4){0.f, 0.f, 0.f, 0.f};
  float mrun = -1e30f, lrun = 0.f;

  for (int t = 0; t < 16; ++t) {
    const int kk0 = t << 6;
    __syncthreads();
#pragma unroll
    for (int p = 0; p < 2; ++p) {
      const int r = row0 + p * 32;
      *(bf16x8*)&Ksm[r * 72 + (ch << 3)] = kr[p];
      *(bf16x8*)&Vsm[r * 72 + (ch << 3)] = vr[p];
    }
    __syncthreads();
    unsigned mvN[4];
    if (t < 15) {                                // prefetch next tile (K/V/mask)
      const int kk1 = kk0 + 64;
#pragma unroll
      for (int p = 0; p < 2; ++p) {
        const int r = row0 + p * 32;
        kr[p] = *(const bf16x8*)(Kp + ((size_t)((kk1 + r) * 8 + b) << 10) + (h << 6) + (ch << 3));
        vr[p] = *(const bf16x8*)(Vg + ((size_t)r << 10) + kk1 + (ch << 3));
      }
      load_mask4(mvN, maskp, mi32, mbase0 + kk1, g);
    }
    // S^T tile: rows kk = mf*16+g*4+j, col q = c
    f32x4 sacc[4];
#pragma unroll
    for (int i = 0; i < 4; ++i) sacc[i] = (f32x4){0.f, 0.f, 0.f, 0.f};
#pragma unroll
    for (int d2 = 0; d2 < 2; ++d2) {
#pragma unroll
      for (int mf = 0; mf < 4; ++mf) {
        bf16x8 kf = *(const bf16x8*)&Ksm[(mf * 16 + c) * 72 + d2 * 32 + (g << 3)];
        sacc[mf] = __builtin_amdgcn_mfma_f32_16x16x32_bf16(kf, qf[d2], sacc[mf], 0, 0, 0);
      }
    }
    // mask + online softmax
    float tmax = -1e30f;
#pragma unroll
    for (int mf = 0; mf < 4; ++mf)
#pragma unroll
      for (int j = 0; j < 4; ++j) {
        float s = sacc[mf][j];
        if ((mv[mf] >> (8 * j)) & 0xffu) s = -1e30f;
        sacc[mf][j] = s;
        tmax = fmaxf(tmax, s);
      }
    tmax = fmaxf(tmax, __shfl_xor(tmax, 16));
    tmax = fmaxf(tmax, __shfl_xor(tmax, 32));
    const float mnew = fmaxf(mrun, tmax);
    const float alpha = __builtin_amdgcn_exp2f((mrun - mnew) * LOG2E);
    float tsum = 0.f;
    float pv[4][4];
#pragma unroll
    for (int mf = 0; mf < 4; ++mf)
#pragma unroll
      for (int j = 0; j < 4; ++j) {
        const float p = __builtin_amdgcn_exp2f((sacc[mf][j] - mnew) * LOG2E);
        pv[mf][j] = p;
        tsum += p;
      }
    tsum += __shfl_xor(tsum, 16);
    tsum += __shfl_xor(tsum, 32);
    lrun = lrun * alpha + tsum;
    mrun = mnew;
#pragma unroll
    for (int i = 0; i < 4; ++i) {
      oacc[i][0] *= alpha; oacc[i][1] *= alpha; oacc[i][2] *= alpha; oacc[i][3] *= alpha;
    }
#pragma unroll
    for (int mf = 0; mf < 4; ++mf) {
      uint2 t2;
      t2.x = pk2(pv[mf][0], pv[mf][1]);
      t2.y = pk2(pv[mf][2], pv[mf][3]);
      *(uint2*)&Psm[w][c * 72 + mf * 16 + (g << 2)] = t2;
    }
#pragma unroll
    for (int ks = 0; ks < 2; ++ks) {
      bf16x8 pf = *(const bf16x8*)&Psm[w][c * 72 + ks * 32 + (g << 3)];
#pragma unroll
      for (int mf = 0; mf < 4; ++mf) {
        bf16x8 vf = *(const bf16x8*)&Vsm[(mf * 16 + c) * 72 + ks * 32 + (g << 3)];
        oacc[mf] = __builtin_amdgcn_mfma_f32_16x16x32_bf16(vf, pf, oacc[mf], 0, 0, 0);
      }
    }
#pragma unroll
    for (int i = 0; i < 4; ++i) mv[i] = mvN[i];
  }
  const float inv = 1.0f / lrun;
#pragma unroll
  for (int mf = 0; mf < 4; ++mf) {
    uint2 t2;
    t2.x = pk2(oacc[mf][0] * inv, oacc[mf][1] * inv);
    t2.y = pk2(oacc[mf][2] * inv, oacc[mf][3] * inv);
    *(uint2*)(AO + ((size_t)(qrow * 8 + b) << 10) + (h << 6) + mf * 16 + (g << 2)) = t2;
  }
}

// ---------------- host ----------------
extern "C" void kernel_launch(void* const* d_in, const int* in_sizes, int n_in,
                              void* d_out, int out_size, void* d_ws, size_t ws_size,
                              hipStream_t stream)
{
  const float* q  = (const float*)d_in[0];
  const float* k  = (const float*)d_in[1];
  const float* v  = (const float*)d_in[2];
  const void*  mask = (const void*)d_in[3];
  const float* wq = (const float*)d_in[4];
  const float* wk = (const float*)d_in[5];
  const float* wv = (const float*)d_in[6];
  const float* wo = (const float*)d_in[7];

  unsigned short* ws  = (unsigned short*)d_ws;   // ~104 MiB used
  unsigned short* Xin = ws;                      // 3 x 8388608 (bf16 q,k,v)
  unsigned short* Wbf = ws + 25165824u;          // 4 x 1048576
  unsigned short* Xp  = ws + 29360128u;          // 3 x 8388608 (projected)
  int* mfl            = (int*)(ws + 54525952u);
  unsigned short* Vt  = ws + 8388608u;           // aliases Xin[1] (dead after K projection)
  unsigned short* AO  = ws;                      // aliases Xin[0] (dead after Q projection)

  detect_mask<<<1, 64, 0, stream>>>((const unsigned*)mask, mfl);
  cvt_kernel<<<14336, 256, 0, stream>>>(q, k, v, wq, wk, wv, wo, Xin, Wbf);
  gemm128<0><<<1536, 256, 0, stream>>>(Xin, Wbf, Xp, 0.125f, 8192, 1024, 1024);   // Q,K,V merged
  transpose_v<<<dim3(16, 128), 256, 0, stream>>>(Xp + 16777216u, Vt);
  attn_kernel<<<dim3(16, 128), 256, 0, stream>>>(Xp, Xp + 8388608u, Vt, mask, mfl, AO);
  gemm128<1><<<512, 256, 0, stream>>>(AO, Wbf + 3145728u, d_out, 1.0f, 8192, 1024, 1024);
}